// Round 8
// baseline (119.409 us; speedup 1.0000x reference)
//
#include <hip/hip_runtime.h>
#include <hip/hip_bf16.h>

#define BT    8192      // B*T tokens (4*2048)
#define SEQ_T 2048
#define DIN   1024
#define NH    16
#define NK    8
#define DH    64
#define DO    64

typedef __bf16 bf16;
typedef __attribute__((ext_vector_type(8))) __bf16 bf16x8;
typedef __attribute__((ext_vector_type(4))) __bf16 bf16x4;
typedef __attribute__((ext_vector_type(4))) float floatx4;

// global -> LDS direct DMA, 16 B per lane (dest = wave-uniform base + lane*16)
#define GLOAD_LDS16(gp, lp)                                        \
  __builtin_amdgcn_global_load_lds(                                \
      (__attribute__((address_space(1))) const void*)(gp),         \
      (__attribute__((address_space(3))) void*)(lp), 16, 0, 0)

// ---------------------------------------------------------------------------
// Kernel A (v13 W-branch verbatim, 128 blocks): W transpose -> swizzled image
//   wimg[(h*2+nh)][R=e*32+o][a], a = (((i>>3) ^ (R&7))<<3) + (i&7)
// ---------------------------------------------------------------------------
__global__ __launch_bounds__(256) void wtrans_kernel(
    const float* __restrict__ weight, bf16* __restrict__ wimg)
{
  __shared__ bf16 tile[64 * 68];
  int hk = blockIdx.x, tid = threadIdx.x;
  int h = hk >> 3, k = hk & 7;
  const float* wsrc = weight + (size_t)hk * DH * DO;
#pragma unroll
  for (int it = 0; it < 4; it++) {
    int idx = it * 1024 + tid * 4;
    int i = idx >> 6, o = idx & 63;
    floatx4 v = *(const floatx4*)(wsrc + idx);
#pragma unroll
    for (int r = 0; r < 4; r++)
      tile[(o + r) * 68 + i] = (bf16)v[r];
  }
  __syncthreads();
#pragma unroll
  for (int it = 0; it < 4; it++) {
    int idx = it * 1024 + tid * 4;
    int o2 = idx >> 6, i2 = idx & 63;
    bf16x4 v = *(const bf16x4*)&tile[o2 * 68 + i2];
    int nh = o2 >> 5, o = o2 & 31, R = k * 32 + o;
    int a = (((i2 >> 3) ^ (R & 7)) << 3) + (i2 & 7);
    *(bf16x4*)(wimg + ((size_t)(h * 2 + nh) * 256 + R) * 64 + a) = v;
  }
}

// ---------------------------------------------------------------------------
// Kernel B (v14): SELF-SUFFICIENT fused block — no cross-block dependency,
// no grid sync, no scores/xh intermediates in global memory.
// Block = (g64: 64-token half-group, hq: head quad), grid 512, 2 blocks/CU.
// Phase 1: scores for the block's 64 tokens x 8 experts, fp32 VALU, math
//   verbatim from the verified prep kernel (bitwise-identical), into sl.
//   4x chip redundancy = 537 MFLOP ~ 3.4 us — cheap vs a dispatch boundary.
// Phase 2: 4 heads x 2 col-halves of v6/v13-verbatim MFMA compute:
//   xl staged from fp32 x (v8 verified convert+swizzle), wl DMA-staged from
//   wimg (v13 verified), sl read in place.
// LDS: xl 8K + wl 32K + sl 2K = 42 KB -> 2 blocks/CU at launch_bounds(256,2).
// XCD-chunked remap: lid = (bid&7)*64 + bid>>3 -> each XCD owns 16
// consecutive g64 (x slices L2-shared by its 4 hq-siblings) + all of wimg.
// ---------------------------------------------------------------------------
__global__ __launch_bounds__(256, 2) void fused_kernel(
    const float* __restrict__ x, const float* __restrict__ diag,
    const float* __restrict__ phi, const bf16* __restrict__ wimg,
    float* __restrict__ out)
{
  __shared__ bf16  xl[64 * 64];         //  8192 B
  __shared__ bf16  wl[256 * 64];        // 32768 B (rows R = e*32 + o)
  __shared__ float sl[NK * 64];         //  2048 B

  int bid = blockIdx.x;
  int lid = ((bid & 7) << 6) | (bid >> 3);   // XCD-chunked, bijective (512=8*64)
  int g64 = lid >> 2;           // 0..127  (64-token half-groups)
  int hq  = lid & 3;            // head quad: heads hq*4 .. hq*4+3
  int tid = threadIdx.x, lane = tid & 63, w = tid >> 6;
  int l15 = lane & 15, q = lane >> 4;

  // ============ phase 1: scores (verbatim prep math, fp32 exact) ============
  {
    const floatx4* dg  = (const floatx4*)diag;
    const floatx4* xr0 = (const floatx4*)(x + (size_t)(g64 * 64 + w * 16) * DIN);
    floatx4 xv[4];
#pragma unroll
    for (int it = 0; it < 4; it++) xv[it] = xr0[it * 64 + lane];
    for (int s = 0; s < 16; s++) {
      floatx4 nx[4];
      if (s < 15) {                       // 2-deep pipeline: next token's row
        const floatx4* nr = xr0 + (size_t)(s + 1) * (DIN / 4);
#pragma unroll
        for (int it = 0; it < 4; it++) nx[it] = nr[it * 64 + lane];
      }
      floatx4 acc[NK];
#pragma unroll
      for (int k = 0; k < NK; k++) acc[k] = (floatx4){0.f, 0.f, 0.f, 0.f};
#pragma unroll
      for (int it = 0; it < 4; it++) {
#pragma unroll
        for (int k = 0; k < NK; k++)
          acc[k] += xv[it] * dg[k * 256 + it * 64 + lane];
      }
      float r[NK];
#pragma unroll
      for (int k = 0; k < NK; k++)
        r[k] = (acc[k][0] + acc[k][1]) + (acc[k][2] + acc[k][3]);
#pragma unroll
      for (int k = 0; k < NK; k++) {
        float v = r[k];
#pragma unroll
        for (int off = 32; off >= 1; off >>= 1) v += __shfl_xor(v, off, 64);
        r[k] = v;
      }
      if (lane == 0) {
        int tl = w * 16 + s;
        int t = (g64 * 64 + tl) & (SEQ_T - 1);
#pragma unroll
        for (int k = 0; k < NK; k++)
          sl[k * 64 + tl] = phi[t * NK + k] + r[k];
      }
      if (s < 15) {
#pragma unroll
        for (int it = 0; it < 4; it++) xv[it] = nx[it];
      }
    }
  }
  __syncthreads();                        // sl complete

  // ============ phase 2: 4 heads x 2 col-halves, v6-verbatim MFMA ============
  int mh = w >> 1;              // 32-token half
  int ns = w & 1;               // 16-col slice within the 32-col half

  auto compute_store = [&](int h, int nh) {
    // B fragments: B[i=ki*32+q*8+j][o=ns*16+l15], all 8 experts
    bf16x8 b[NK][2];
#pragma unroll
    for (int e = 0; e < NK; e++) {
      int R = e * 32 + ns * 16 + l15;
#pragma unroll
      for (int ki = 0; ki < 2; ki++) {
        int pc = (ki * 4 + q) ^ (R & 7);
        b[e][ki] = *(const bf16x8*)(wl + R * 64 + pc * 8);
      }
    }
#pragma unroll
    for (int m = 0; m < 2; m++) {
      int tr = mh * 32 + m * 16;                 // token row base (0..48)
      int row = tr + l15;
      int p0 = q ^ (row & 7), p1 = (q + 4) ^ (row & 7);
      bf16x8 a0 = *(const bf16x8*)(xl + row * 64 + p0 * 8);
      bf16x8 a1 = *(const bf16x8*)(xl + row * 64 + p1 * 8);
      floatx4 y = (floatx4){0.f, 0.f, 0.f, 0.f};
#pragma unroll
      for (int e = 0; e < NK; e++) {
        floatx4 s4 = *(const floatx4*)(sl + e * 64 + tr + q * 4);
        floatx4 z = (floatx4){0.f, 0.f, 0.f, 0.f};
        z = __builtin_amdgcn_mfma_f32_16x16x32_bf16(a0, b[e][0], z, 0, 0, 0);
        z = __builtin_amdgcn_mfma_f32_16x16x32_bf16(a1, b[e][1], z, 0, 0, 0);
        y += s4 * z;
      }
      int orow = g64 * 64 + tr + q * 4;          // C/D: col=l15, row=q*4+r
      float* op = out + (size_t)orow * (NH * DO) + h * DO + nh * 32
                      + ns * 16 + l15;
#pragma unroll
      for (int r = 0; r < 4; r++)
        op[(size_t)r * (NH * DO)] = y[r];
    }
  };

  for (int hh = 0; hh < 4; hh++) {
    int h = hq * 4 + hh;
    if (hh) __syncthreads();              // prev iter's xl/wl readers done

    // ---- stage xl: 64x64 from fp32 x, convert + swizzle (v8 verified) ----
    {
      const float* xs = x + (size_t)(g64 * 64) * DIN + h * 64;
#pragma unroll
      for (int it = 0; it < 2; it++) {
        int idx = it * 256 + tid;           // chunk 0..511
        int row = idx >> 3, c = idx & 7;
        const float* p = xs + (size_t)row * DIN + c * 8;
        floatx4 u0 = *(const floatx4*)p;
        floatx4 u1 = *(const floatx4*)(p + 4);
        bf16x8 v;
        v[0] = (bf16)u0[0]; v[1] = (bf16)u0[1];
        v[2] = (bf16)u0[2]; v[3] = (bf16)u0[3];
        v[4] = (bf16)u1[0]; v[5] = (bf16)u1[1];
        v[6] = (bf16)u1[2]; v[7] = (bf16)u1[3];
        *(bf16x8*)(xl + row * 64 + ((c ^ (row & 7)) << 3)) = v;
      }
    }
    // ---- stage wl (h, nh=0): 8 DMA issues (v13 verified) ----
    {
      const bf16* ws = wimg + (size_t)(h * 2 + 0) * 16384;
#pragma unroll
      for (int it = 0; it < 8; it++)
        GLOAD_LDS16(ws + it * 2048 + tid * 8, wl + it * 2048 + tid * 8);
    }
    __syncthreads();                      // xl + wl0 resident
    compute_store(h, 0);
    __syncthreads();                      // wl readers done
    // ---- stage wl (h, nh=1) ----
    {
      const bf16* ws = wimg + (size_t)(h * 2 + 1) * 16384;
#pragma unroll
      for (int it = 0; it < 8; it++)
        GLOAD_LDS16(ws + it * 2048 + tid * 8, wl + it * 2048 + tid * 8);
    }
    __syncthreads();                      // wl1 resident
    compute_store(h, 1);
  }
}

extern "C" void kernel_launch(void* const* d_in, const int* in_sizes, int n_in,
                              void* d_out, int out_size, void* d_ws, size_t ws_size,
                              hipStream_t stream) {
  const float* x      = (const float*)d_in[0];
  const float* weight = (const float*)d_in[1];
  const float* diag   = (const float*)d_in[2];
  const float* phi    = (const float*)d_in[3];
  float* out = (float*)d_out;

  bf16* wimg = (bf16*)d_ws;               // 1 MiB swizzled W image

  wtrans_kernel<<<NH * NK, 256, 0, stream>>>(weight, wimg);
  // 128 token-half-groups x 4 head-quads (XCD-remapped in-kernel)
  fused_kernel<<<512, 256, 0, stream>>>(x, diag, phi, wimg, out);
}